// Round 1
// baseline (397.742 us; speedup 1.0000x reference)
//
#include <hip/hip_runtime.h>

#define BATCH 8192
#define MEXP  64
#define HDIM  256
#define INDIM 3
#define ODIM  3
#define BT    64
#define SINSC 4.774648292756860f   /* 30 / (2*pi): sin(30 z) = v_sin(z*SINSC) */

typedef __attribute__((ext_vector_type(8))) _Float16 f16x8;
typedef __attribute__((ext_vector_type(4))) float    f32x4;

// Swizzled LDS byte offset for h[row][colByte]. XOR of ((row ^ row>>3)&7) into byte
// bits 4:6 — bijective within each row, identical on write & read sides, spreads the
// stride-512B ds_read_b128 A-fragment pattern across banks (2-way max, free).
__device__ __forceinline__ int swz(int row, int byteInRow) {
  return (row * 512 + byteInRow) ^ (((row ^ (row >> 3)) & 7) << 4);
}

// ---------- weight preprocessing: fp32 -> fp16 in MFMA B-fragment order ----------
// Hidden layers. Per (layer,m): chunk c = (ct*8+ks)*64+lane holds
// w[m][ct*16+(lane&15)][ks*32+(lane>>4)*8 + j], j=0..7  (B-frag for 16x16x32).
__global__ void prep_hidden(const float* __restrict__ w1, const float* __restrict__ w2,
                            const float* __restrict__ w3, _Float16* __restrict__ ws) {
  int chunk = blockIdx.x * 256 + threadIdx.x;   // 3*64*8192 chunks of 8 elements
  int lm    = chunk >> 13;                      // layer*64 + m
  int c     = chunk & 8191;
  int layer = lm >> 6, m = lm & 63;
  int lane  = c & 63;
  int ctks  = c >> 6;
  int ct = ctks >> 3, ks = ctks & 7;
  int col = ct * 16 + (lane & 15);
  int k   = ks * 32 + ((lane >> 4) << 3);
  const float* w = (layer == 0) ? w1 : (layer == 1) ? w2 : w3;
  const float* src = w + ((size_t)m * HDIM + col) * HDIM + k;
  f16x8 v;
#pragma unroll
  for (int j = 0; j < 8; ++j) v[j] = (_Float16)src[j];
  *(f16x8*)(ws + (size_t)chunk * 8) = v;
}

// Final layer wf[m][o][k] -> 16x16x32 B-frags with cols 3..15 zero-padded.
__global__ void prep_wf(const float* __restrict__ wf, _Float16* __restrict__ ws) {
  int chunk = blockIdx.x * 256 + threadIdx.x;   // 64*512 chunks
  int m    = chunk >> 9;
  int c    = chunk & 511;                       // ks*64 + lane
  int lane = c & 63;
  int ks   = c >> 6;
  int col  = lane & 15;
  int k    = ks * 32 + ((lane >> 4) << 3);
  f16x8 v;
  if (col < ODIM) {
    const float* src = wf + ((size_t)m * ODIM + col) * HDIM + k;
#pragma unroll
    for (int j = 0; j < 8; ++j) v[j] = (_Float16)src[j];
  } else {
#pragma unroll
    for (int j = 0; j < 8; ++j) v[j] = (_Float16)0.0f;
  }
  *(f16x8*)(ws + (size_t)chunk * 8) = v;
}

// ---------- fused SIREN ----------
// One hidden layer: h(LDS) -> MFMA vs fragment-ordered weights (global/L2) -> sin -> h(LDS).
__device__ __forceinline__ void hidden_layer(char* hb, const _Float16* __restrict__ wl,
                                             const float* __restrict__ bptr, int w, int lane) {
  f32x4 acc[4][4] = {};
#pragma unroll
  for (int ks = 0; ks < 8; ++ks) {
    f16x8 a[4];
    f16x8 bb[4];
#pragma unroll
    for (int rt = 0; rt < 4; ++rt) {
      int row = rt * 16 + (lane & 15);
      a[rt] = *(const f16x8*)(hb + swz(row, ks * 64 + ((lane >> 4) << 4)));
    }
#pragma unroll
    for (int ct = 0; ct < 4; ++ct) {
      int chunk = ((w * 4 + ct) * 8 + ks) * 64 + lane;   // coalesced 1KB per load
      bb[ct] = *(const f16x8*)(wl + chunk * 8);
    }
#pragma unroll
    for (int rt = 0; rt < 4; ++rt)
#pragma unroll
      for (int ct = 0; ct < 4; ++ct)
        acc[rt][ct] = __builtin_amdgcn_mfma_f32_16x16x32_f16(a[rt], bb[ct], acc[rt][ct], 0, 0, 0);
  }
  __syncthreads();   // all A-reads of hb complete before overwrite
#pragma unroll
  for (int ct = 0; ct < 4; ++ct) {
    int col = w * 64 + ct * 16 + (lane & 15);
    float bias = bptr[col];
#pragma unroll
    for (int rt = 0; rt < 4; ++rt) {
#pragma unroll
      for (int t = 0; t < 4; ++t) {
        int row = rt * 16 + ((lane >> 4) << 2) + t;   // C/D: col=lane&15, row=(lane>>4)*4+t
        float h = __builtin_amdgcn_sinf((acc[rt][ct][t] + bias) * SINSC);
        *(_Float16*)(hb + swz(row, col * 2)) = (_Float16)h;
      }
    }
  }
  __syncthreads();
}

__global__ __launch_bounds__(256, 2)
void siren_fused(const float* __restrict__ x, const float* __restrict__ w0,
                 const float* __restrict__ b0, const float* __restrict__ b1,
                 const float* __restrict__ b2, const float* __restrict__ b3,
                 const float* __restrict__ bfin, const _Float16* __restrict__ wh,
                 const _Float16* __restrict__ wff, float* __restrict__ out) {
  __shared__ _Float16 hbuf[BT * HDIM];   // 32 KB, swizzled fp16 h tile
  char* hb = (char*)hbuf;

  int tid  = threadIdx.x;
  int lane = tid & 63;
  int w    = tid >> 6;
  int id   = blockIdx.x;
  // XCD swizzle: dispatch round-robins XCD = id%8; give each XCD 8 experts so the
  // per-XCD L2 weight working set is 8*3*128KB = 3MB < 4MB.
  int m    = ((id & 7) << 3) + ((id >> 3) >> 7);
  int tile = (id >> 3) & 127;

  // ---- layer 0: [BT,3] x w0[m][H,3]^T, pure fp32 VALU (K=3) ----
  {
    int col = tid;  // 256 threads = 256 cols
    const float* wp = w0 + ((size_t)m * HDIM + col) * INDIM;
    float wc0 = wp[0], wc1 = wp[1], wc2 = wp[2];
    float bc  = b0[m * HDIM + col];
    const float* xp = x + (size_t)tile * BT * INDIM;   // uniform across block -> s_load
#pragma unroll 4
    for (int r = 0; r < BT; ++r) {
      float z = fmaf(xp[r * 3 + 2], wc2, fmaf(xp[r * 3 + 1], wc1, fmaf(xp[r * 3], wc0, bc)));
      float h = __builtin_amdgcn_sinf(z * SINSC);
      *(_Float16*)(hb + swz(r, col * 2)) = (_Float16)h;
    }
  }
  __syncthreads();

  hidden_layer(hb, wh + ((size_t)0 * MEXP + m) * (HDIM * HDIM), b1 + m * HDIM, w, lane);
  hidden_layer(hb, wh + ((size_t)1 * MEXP + m) * (HDIM * HDIM), b2 + m * HDIM, w, lane);
  hidden_layer(hb, wh + ((size_t)2 * MEXP + m) * (HDIM * HDIM), b3 + m * HDIM, w, lane);

  // ---- final layer: one 16-col MFMA strip per wave (cols 0..2 used) ----
  {
    f32x4 facc = {};
    const _Float16* wfp = wff + (size_t)m * (16 * HDIM);
#pragma unroll
    for (int ks = 0; ks < 8; ++ks) {
      int row = w * 16 + (lane & 15);
      f16x8 a   = *(const f16x8*)(hb + swz(row, ks * 64 + ((lane >> 4) << 4)));
      f16x8 bfr = *(const f16x8*)(wfp + ((size_t)(ks * 64 + lane)) * 8);
      facc = __builtin_amdgcn_mfma_f32_16x16x32_f16(a, bfr, facc, 0, 0, 0);
    }
    int col = lane & 15;
    if (col < ODIM) {
      float bv = bfin[m * ODIM + col];
#pragma unroll
      for (int t = 0; t < 4; ++t) {
        int row = w * 16 + ((lane >> 4) << 2) + t;
        int b   = tile * BT + row;
        out[((size_t)b * MEXP + m) * ODIM + col] = facc[t] + bv;
      }
    }
  }
}

extern "C" void kernel_launch(void* const* d_in, const int* in_sizes, int n_in,
                              void* d_out, int out_size, void* d_ws, size_t ws_size,
                              hipStream_t stream) {
  (void)in_sizes; (void)n_in; (void)out_size; (void)ws_size;
  const float* x  = (const float*)d_in[0];
  const float* w0 = (const float*)d_in[1];
  const float* b0 = (const float*)d_in[2];
  const float* w1 = (const float*)d_in[3];
  const float* b1 = (const float*)d_in[4];
  const float* w2 = (const float*)d_in[5];
  const float* b2 = (const float*)d_in[6];
  const float* w3 = (const float*)d_in[7];
  const float* b3 = (const float*)d_in[8];
  const float* wf = (const float*)d_in[9];
  const float* bf = (const float*)d_in[10];

  _Float16* wh  = (_Float16*)d_ws;                       // 3*64*65536 fp16 = 24 MB
  _Float16* wff = wh + (size_t)3 * MEXP * HDIM * HDIM;   // + 64*4096 fp16 = 0.5 MB

  prep_hidden<<<6144, 256, 0, stream>>>(w1, w2, w3, wh);
  prep_wf<<<128, 256, 0, stream>>>(wf, wff);
  siren_fused<<<8192, 256, 0, stream>>>(x, w0, b0, b1, b2, b3, bf, wh, wff, (float*)d_out);
}